// Round 1
// baseline (260.761 us; speedup 1.0000x reference)
//
#include <hip/hip_runtime.h>
#include <hip/hip_bf16.h>

// L=4096, B=16, C_IN=512, C_OUT=512, C_COND=512, K=4, HID=128, T=30
typedef __bf16 bfx8 __attribute__((ext_vector_type(8)));
typedef float f32x4 __attribute__((ext_vector_type(4)));
typedef unsigned short u16x8 __attribute__((ext_vector_type(8)));
typedef unsigned short u16x4 __attribute__((ext_vector_type(4)));

__device__ __forceinline__ unsigned short f2bf(float f) {
    unsigned int u = __builtin_bit_cast(unsigned int, f);
    u += 0x7fffu + ((u >> 16) & 1u);          // RNE
    return (unsigned short)(u >> 16);
}

// ---------- kernel 1: conditioning MLP -> att (16x4) and b_agg (16x512) ----------
__global__ __launch_bounds__(1024) void att_kernel(
    const float* __restrict__ cond, const float* __restrict__ fc1w,
    const float* __restrict__ fc1b, const float* __restrict__ fc2w,
    const float* __restrict__ fc2b, const float* __restrict__ bias,
    float* __restrict__ att_out, float* __restrict__ bagg_out)
{
    __shared__ float h[16][128];
    __shared__ float att[16][4];
    const int tid = threadIdx.x;

    for (int t = tid; t < 16 * 128; t += 1024) {
        const int b = t >> 7, j = t & 127;
        const float* c = cond + b * 512;
        const float* w = fc1w + j * 512;
        float s = fc1b[j];
        #pragma unroll 8
        for (int i = 0; i < 512; ++i) s += c[i] * w[i];
        h[b][j] = fmaxf(s, 0.0f);
    }
    __syncthreads();
    if (tid < 64) {
        const int b = tid >> 2, k = tid & 3;
        float s = fc2b[k];
        #pragma unroll
        for (int j = 0; j < 128; ++j) s += h[b][j] * fc2w[k * 128 + j];
        att[b][k] = s * (1.0f / 30.0f);
    }
    __syncthreads();
    if (tid < 16) {
        const int b = tid;
        float l0 = att[b][0], l1 = att[b][1], l2 = att[b][2], l3 = att[b][3];
        float m = fmaxf(fmaxf(l0, l1), fmaxf(l2, l3));
        float e0 = expf(l0 - m), e1 = expf(l1 - m), e2 = expf(l2 - m), e3 = expf(l3 - m);
        float inv = 1.0f / (e0 + e1 + e2 + e3);
        att[b][0] = e0 * inv; att[b][1] = e1 * inv;
        att[b][2] = e2 * inv; att[b][3] = e3 * inv;
        att_out[b * 4 + 0] = att[b][0]; att_out[b * 4 + 1] = att[b][1];
        att_out[b * 4 + 2] = att[b][2]; att_out[b * 4 + 3] = att[b][3];
    }
    __syncthreads();
    for (int t = tid; t < 16 * 512; t += 1024) {
        const int b = t >> 9, o = t & 511;
        bagg_out[t] = att[b][0] * bias[o] + att[b][1] * bias[512 + o]
                    + att[b][2] * bias[1024 + o] + att[b][3] * bias[1536 + o];
    }
}

// ---------- kernel 2: w_agg[b][o][i] = sum_k att[b][k]*weight[k][o][i], bf16 ----------
__global__ __launch_bounds__(256) void wagg_kernel(
    const float* __restrict__ weight, const float* __restrict__ att,
    unsigned short* __restrict__ wagg)
{
    __shared__ float a_s[64];
    if (threadIdx.x < 64) a_s[threadIdx.x] = att[threadIdx.x];
    __syncthreads();
    const int p = (blockIdx.x * 256 + threadIdx.x) * 4;   // 0..262143, *4 contiguous
    const float4 w0 = *(const float4*)(weight + p);
    const float4 w1 = *(const float4*)(weight + 262144 + p);
    const float4 w2 = *(const float4*)(weight + 524288 + p);
    const float4 w3 = *(const float4*)(weight + 786432 + p);
    #pragma unroll
    for (int b = 0; b < 16; ++b) {
        const float a0 = a_s[4 * b], a1 = a_s[4 * b + 1], a2 = a_s[4 * b + 2], a3 = a_s[4 * b + 3];
        u16x4 r;
        r[0] = f2bf(a0 * w0.x + a1 * w1.x + a2 * w2.x + a3 * w3.x);
        r[1] = f2bf(a0 * w0.y + a1 * w1.y + a2 * w2.y + a3 * w3.y);
        r[2] = f2bf(a0 * w0.z + a1 * w1.z + a2 * w2.z + a3 * w3.z);
        r[3] = f2bf(a0 * w0.w + a1 * w1.w + a2 * w2.w + a3 * w3.w);
        *(u16x4*)(wagg + (size_t)b * 262144 + p) = r;
    }
}

// ---------- kernel 3: out[l][b][o] = sum_i x[l][b][i]*wagg[b][o][i] + bagg[b][o] ----------
// Tile: BM=128 (L), BN=512 (all C_OUT), BK=32. 512 threads = 8 waves (2m x 4n),
// wave tile 64x128. A reg-staged fp32->bf16; B via global_load_lds (bf16 in ws).
__global__ __launch_bounds__(512, 2) void gemm_kernel(
    const float* __restrict__ x, const unsigned short* __restrict__ wagg,
    const float* __restrict__ bagg, float* __restrict__ out)
{
    __shared__ unsigned short As[128 * 32];
    __shared__ unsigned short Bs[512 * 32];
    __shared__ float bsh[512];

    const int tid = threadIdx.x;
    const int bid = blockIdx.x;
    const int b  = bid >> 5;          // 0..15 (b-major: same-b blocks share wagg[b] in L2)
    const int l0 = (bid & 31) * 128;  // L tile origin

    const int lane = tid & 63;
    const int wid  = tid >> 6;        // 0..7
    const int wm   = wid >> 2;        // 0..1
    const int wn   = wid & 3;         // 0..3
    const int fr   = lane & 15;
    const int fq   = lane >> 4;

    const unsigned short* wb = wagg + (size_t)b * (512 * 512);

    bsh[tid] = bagg[b * 512 + tid];

    f32x4 acc[4][8];
    #pragma unroll
    for (int i = 0; i < 4; ++i)
        #pragma unroll
        for (int j = 0; j < 8; ++j) acc[i][j] = f32x4{0.f, 0.f, 0.f, 0.f};

    // A staging: thread covers 8 consecutive floats of the 128x32 tile
    const int ea   = tid * 8;
    const int arow = ea >> 5, acol = ea & 31;
    const float* xsrc = x + ((size_t)(l0 + arow) * 16 + b) * 512 + acol;

    for (int kt = 0; kt < 16; ++kt) {
        const int k0 = kt * 32;
        __syncthreads();   // previous iter's LDS reads done
        // --- stage A (fp32 -> bf16, ds_write_b128) ---
        {
            const float4 v0 = *(const float4*)(xsrc + k0);
            const float4 v1 = *(const float4*)(xsrc + k0 + 4);
            u16x8 pk;
            pk[0] = f2bf(v0.x); pk[1] = f2bf(v0.y); pk[2] = f2bf(v0.z); pk[3] = f2bf(v0.w);
            pk[4] = f2bf(v1.x); pk[5] = f2bf(v1.y); pk[6] = f2bf(v1.z); pk[7] = f2bf(v1.w);
            *(u16x8*)&As[ea] = pk;
        }
        // --- stage B (global_load_lds x4, 16B/lane, linear LDS) ---
        #pragma unroll
        for (int it = 0; it < 4; ++it) {
            const int e   = tid * 8 + it * 4096;
            const int row = e >> 5, col = e & 31;
            const unsigned short* g = wb + (size_t)row * 512 + k0 + col;
            char* dst = (char*)Bs + tid * 16 + it * 8192;  // linear: lane order == lds order
            __builtin_amdgcn_global_load_lds(
                (const __attribute__((address_space(1))) void*)g,
                (__attribute__((address_space(3))) void*)dst, 16, 0, 0);
        }
        __syncthreads();
        // --- fragments + MFMA ---
        bfx8 af[4], bfr[8];
        #pragma unroll
        for (int mf = 0; mf < 4; ++mf)
            af[mf] = *reinterpret_cast<const bfx8*>(&As[(wm * 64 + mf * 16 + fr) * 32 + fq * 8]);
        #pragma unroll
        for (int nf = 0; nf < 8; ++nf)
            bfr[nf] = *reinterpret_cast<const bfx8*>(&Bs[(wn * 128 + nf * 16 + fr) * 32 + fq * 8]);
        #pragma unroll
        for (int mf = 0; mf < 4; ++mf)
            #pragma unroll
            for (int nf = 0; nf < 8; ++nf)
                acc[mf][nf] = __builtin_amdgcn_mfma_f32_16x16x32_bf16(af[mf], bfr[nf], acc[mf][nf], 0, 0, 0);
    }

    // --- epilogue: C/D map col=lane&15 (n), row=(lane>>4)*4+r (m) ---
    #pragma unroll
    for (int mf = 0; mf < 4; ++mf) {
        #pragma unroll
        for (int nf = 0; nf < 8; ++nf) {
            const int o = wn * 128 + nf * 16 + fr;
            const float bb = bsh[o];
            const int lrow = l0 + wm * 64 + mf * 16 + fq * 4;
            float* op = out + ((size_t)lrow * 16 + b) * 512 + o;
            const f32x4 a = acc[mf][nf];
            op[0]         = a[0] + bb;
            op[8192]      = a[1] + bb;   // next l: +B*C_OUT = 8192 floats
            op[2 * 8192]  = a[2] + bb;
            op[3 * 8192]  = a[3] + bb;
        }
    }
}

extern "C" void kernel_launch(void* const* d_in, const int* in_sizes, int n_in,
                              void* d_out, int out_size, void* d_ws, size_t ws_size,
                              hipStream_t stream) {
    const float* x      = (const float*)d_in[0];
    const float* cond   = (const float*)d_in[1];
    const float* fc1w   = (const float*)d_in[2];
    const float* fc1b   = (const float*)d_in[3];
    const float* fc2w   = (const float*)d_in[4];
    const float* fc2b   = (const float*)d_in[5];
    const float* weight = (const float*)d_in[6];
    const float* bias   = (const float*)d_in[7];
    float* out = (float*)d_out;

    char* ws = (char*)d_ws;
    float* att_ws  = (float*)ws;                       // 64 f32
    float* bagg_ws = (float*)(ws + 1024);              // 8192 f32
    unsigned short* wagg_ws = (unsigned short*)(ws + 65536);  // 16*512*512 bf16 = 8 MiB

    att_kernel<<<1, 1024, 0, stream>>>(cond, fc1w, fc1b, fc2w, fc2b, bias, att_ws, bagg_ws);
    wagg_kernel<<<256, 256, 0, stream>>>(weight, att_ws, wagg_ws);
    gemm_kernel<<<512, 512, 0, stream>>>(x, wagg_ws, bagg_ws, out);
}

// Round 3
// 170.862 us; speedup vs baseline: 1.5262x; 1.5262x over previous
//
#include <hip/hip_runtime.h>
#include <hip/hip_bf16.h>

// L=4096, B=16, C_IN=512, C_OUT=512, C_COND=512, K=4, HID=128, T=30
typedef __bf16 bfx8 __attribute__((ext_vector_type(8)));
typedef float f32x4 __attribute__((ext_vector_type(4)));
typedef unsigned short u16x8 __attribute__((ext_vector_type(8)));
typedef unsigned short u16x4 __attribute__((ext_vector_type(4)));

__device__ __forceinline__ unsigned short f2bf(float f) {
    unsigned int u = __builtin_bit_cast(unsigned int, f);
    u += 0x7fffu + ((u >> 16) & 1u);          // RNE
    return (unsigned short)(u >> 16);
}

// ---------- kernel 1: conditioning MLP -> att (16x4) and b_agg (16x512) ----------
// fc1: one wave per (b,j) output, 64 lanes x 8 floats coalesced.
// fc2: one wave per b, k-loop inside.
__global__ __launch_bounds__(1024) void att_kernel(
    const float* __restrict__ cond, const float* __restrict__ fc1w,
    const float* __restrict__ fc1b, const float* __restrict__ fc2w,
    const float* __restrict__ fc2b, const float* __restrict__ bias,
    float* __restrict__ att_out, float* __restrict__ bagg_out)
{
    __shared__ float h[16][128];
    __shared__ float att[16][4];
    const int tid  = threadIdx.x;
    const int lane = tid & 63;
    const int wv   = tid >> 6;          // 0..15

    // fc1: 2048 outputs, one wave each, 128 iterations per wave
    for (int p = wv; p < 16 * 128; p += 16) {
        const int b = p >> 7, j = p & 127;
        const float* c = cond + b * 512 + lane * 8;
        const float* w = fc1w + j * 512 + lane * 8;
        const float4 c0 = *(const float4*)c,       c1 = *(const float4*)(c + 4);
        const float4 w0 = *(const float4*)w,       w1 = *(const float4*)(w + 4);
        float s = c0.x * w0.x + c0.y * w0.y + c0.z * w0.z + c0.w * w0.w
                + c1.x * w1.x + c1.y * w1.y + c1.z * w1.z + c1.w * w1.w;
        #pragma unroll
        for (int off = 32; off; off >>= 1) s += __shfl_down(s, off);
        if (lane == 0) h[b][j] = fmaxf(s + fc1b[j], 0.0f);
    }
    __syncthreads();

    // fc2: one wave per b (16 waves), each wave computes k=0..3
    {
        const int b = wv;
        const float hv0 = h[b][lane], hv1 = h[b][lane + 64];
        #pragma unroll
        for (int k = 0; k < 4; ++k) {
            const float* w = fc2w + k * 128;
            float s = hv0 * w[lane] + hv1 * w[lane + 64];
            #pragma unroll
            for (int off = 32; off; off >>= 1) s += __shfl_down(s, off);
            if (lane == 0) att[b][k] = (s + fc2b[k]) * (1.0f / 30.0f);
        }
    }
    __syncthreads();

    if (tid < 16) {
        const int b = tid;
        float l0 = att[b][0], l1 = att[b][1], l2 = att[b][2], l3 = att[b][3];
        float m = fmaxf(fmaxf(l0, l1), fmaxf(l2, l3));
        float e0 = expf(l0 - m), e1 = expf(l1 - m), e2 = expf(l2 - m), e3 = expf(l3 - m);
        float inv = 1.0f / (e0 + e1 + e2 + e3);
        att[b][0] = e0 * inv; att[b][1] = e1 * inv;
        att[b][2] = e2 * inv; att[b][3] = e3 * inv;
        att_out[b * 4 + 0] = att[b][0]; att_out[b * 4 + 1] = att[b][1];
        att_out[b * 4 + 2] = att[b][2]; att_out[b * 4 + 3] = att[b][3];
    }
    __syncthreads();

    for (int t = tid; t < 16 * 512; t += 1024) {
        const int b = t >> 9, o = t & 511;
        bagg_out[t] = att[b][0] * bias[o] + att[b][1] * bias[512 + o]
                    + att[b][2] * bias[1024 + o] + att[b][3] * bias[1536 + o];
    }
}

// ---------- kernel 2: w_agg[b][o][i] = sum_k att[b][k]*weight[k][o][i], bf16 ----------
__global__ __launch_bounds__(256) void wagg_kernel(
    const float* __restrict__ weight, const float* __restrict__ att,
    unsigned short* __restrict__ wagg)
{
    __shared__ float a_s[64];
    if (threadIdx.x < 64) a_s[threadIdx.x] = att[threadIdx.x];
    __syncthreads();
    const int p = (blockIdx.x * 256 + threadIdx.x) * 4;   // 0..262143, *4 contiguous
    const float4 w0 = *(const float4*)(weight + p);
    const float4 w1 = *(const float4*)(weight + 262144 + p);
    const float4 w2 = *(const float4*)(weight + 524288 + p);
    const float4 w3 = *(const float4*)(weight + 786432 + p);
    #pragma unroll
    for (int b = 0; b < 16; ++b) {
        const float a0 = a_s[4 * b], a1 = a_s[4 * b + 1], a2 = a_s[4 * b + 2], a3 = a_s[4 * b + 3];
        u16x4 r;
        r[0] = f2bf(a0 * w0.x + a1 * w1.x + a2 * w2.x + a3 * w3.x);
        r[1] = f2bf(a0 * w0.y + a1 * w1.y + a2 * w2.y + a3 * w3.y);
        r[2] = f2bf(a0 * w0.z + a1 * w1.z + a2 * w2.z + a3 * w3.z);
        r[3] = f2bf(a0 * w0.w + a1 * w1.w + a2 * w2.w + a3 * w3.w);
        *(u16x4*)(wagg + (size_t)b * 262144 + p) = r;
    }
}

// ---------- kernel 3: out[l][b][o] = sum_i x[l][b][i]*wagg[b][o][i] + bagg[b][o] ----------
// Tile: BM=128 (L), BN=512 (all C_OUT), BK=32. 512 threads = 8 waves (2m x 4n),
// wave tile 64x128. A reg-staged fp32->bf16; B via global_load_lds (bf16 in ws).
__global__ __launch_bounds__(512, 2) void gemm_kernel(
    const float* __restrict__ x, const unsigned short* __restrict__ wagg,
    const float* __restrict__ bagg, float* __restrict__ out)
{
    __shared__ unsigned short As[128 * 32];
    __shared__ unsigned short Bs[512 * 32];
    __shared__ float bsh[512];

    const int tid = threadIdx.x;
    const int bid = blockIdx.x;
    const int b  = bid >> 5;          // 0..15 (b-major: same-b blocks share wagg[b] in L2)
    const int l0 = (bid & 31) * 128;  // L tile origin

    const int lane = tid & 63;
    const int wid  = tid >> 6;        // 0..7
    const int wm   = wid >> 2;        // 0..1
    const int wn   = wid & 3;         // 0..3
    const int fr   = lane & 15;
    const int fq   = lane >> 4;

    const unsigned short* wb = wagg + (size_t)b * (512 * 512);

    bsh[tid] = bagg[b * 512 + tid];

    f32x4 acc[4][8];
    #pragma unroll
    for (int i = 0; i < 4; ++i)
        #pragma unroll
        for (int j = 0; j < 8; ++j) acc[i][j] = f32x4{0.f, 0.f, 0.f, 0.f};

    // A staging: thread covers 8 consecutive floats of the 128x32 tile
    const int ea   = tid * 8;
    const int arow = ea >> 5, acol = ea & 31;
    const float* xsrc = x + ((size_t)(l0 + arow) * 16 + b) * 512 + acol;

    for (int kt = 0; kt < 16; ++kt) {
        const int k0 = kt * 32;
        __syncthreads();   // previous iter's LDS reads done
        // --- stage A (fp32 -> bf16, ds_write_b128) ---
        {
            const float4 v0 = *(const float4*)(xsrc + k0);
            const float4 v1 = *(const float4*)(xsrc + k0 + 4);
            u16x8 pk;
            pk[0] = f2bf(v0.x); pk[1] = f2bf(v0.y); pk[2] = f2bf(v0.z); pk[3] = f2bf(v0.w);
            pk[4] = f2bf(v1.x); pk[5] = f2bf(v1.y); pk[6] = f2bf(v1.z); pk[7] = f2bf(v1.w);
            *(u16x8*)&As[ea] = pk;
        }
        // --- stage B (global_load_lds x4, 16B/lane, linear LDS) ---
        #pragma unroll
        for (int it = 0; it < 4; ++it) {
            const int e   = tid * 8 + it * 4096;
            const int row = e >> 5, col = e & 31;
            const unsigned short* g = wb + (size_t)row * 512 + k0 + col;
            char* dst = (char*)Bs + tid * 16 + it * 8192;  // linear: lane order == lds order
            __builtin_amdgcn_global_load_lds(
                (const __attribute__((address_space(1))) void*)g,
                (__attribute__((address_space(3))) void*)dst, 16, 0, 0);
        }
        __syncthreads();
        // --- fragments + MFMA ---
        bfx8 af[4], bfr[8];
        #pragma unroll
        for (int mf = 0; mf < 4; ++mf)
            af[mf] = *reinterpret_cast<const bfx8*>(&As[(wm * 64 + mf * 16 + fr) * 32 + fq * 8]);
        #pragma unroll
        for (int nf = 0; nf < 8; ++nf)
            bfr[nf] = *reinterpret_cast<const bfx8*>(&Bs[(wn * 128 + nf * 16 + fr) * 32 + fq * 8]);
        #pragma unroll
        for (int mf = 0; mf < 4; ++mf)
            #pragma unroll
            for (int nf = 0; nf < 8; ++nf)
                acc[mf][nf] = __builtin_amdgcn_mfma_f32_16x16x32_bf16(af[mf], bfr[nf], acc[mf][nf], 0, 0, 0);
    }

    // --- epilogue: C/D map col=lane&15 (n), row=(lane>>4)*4+r (m) ---
    #pragma unroll
    for (int mf = 0; mf < 4; ++mf) {
        #pragma unroll
        for (int nf = 0; nf < 8; ++nf) {
            const int o = wn * 128 + nf * 16 + fr;
            const float bb = bsh[o];
            const int lrow = l0 + wm * 64 + mf * 16 + fq * 4;
            float* op = out + ((size_t)lrow * 16 + b) * 512 + o;
            const f32x4 a = acc[mf][nf];
            op[0]         = a[0] + bb;
            op[8192]      = a[1] + bb;   // next l: +B*C_OUT = 8192 floats
            op[2 * 8192]  = a[2] + bb;
            op[3 * 8192]  = a[3] + bb;
        }
    }
}

extern "C" void kernel_launch(void* const* d_in, const int* in_sizes, int n_in,
                              void* d_out, int out_size, void* d_ws, size_t ws_size,
                              hipStream_t stream) {
    const float* x      = (const float*)d_in[0];
    const float* cond   = (const float*)d_in[1];
    const float* fc1w   = (const float*)d_in[2];
    const float* fc1b   = (const float*)d_in[3];
    const float* fc2w   = (const float*)d_in[4];
    const float* fc2b   = (const float*)d_in[5];
    const float* weight = (const float*)d_in[6];
    const float* bias   = (const float*)d_in[7];
    float* out = (float*)d_out;

    char* ws = (char*)d_ws;
    float* att_ws  = (float*)ws;                       // 64 f32
    float* bagg_ws = (float*)(ws + 1024);              // 8192 f32
    unsigned short* wagg_ws = (unsigned short*)(ws + 65536);  // 16*512*512 bf16 = 8 MiB

    att_kernel<<<1, 1024, 0, stream>>>(cond, fc1w, fc1b, fc2w, fc2b, bias, att_ws, bagg_ws);
    wagg_kernel<<<256, 256, 0, stream>>>(weight, att_ws, wagg_ws);
    gemm_kernel<<<512, 512, 0, stream>>>(x, wagg_ws, bagg_ws, out);
}

// Round 4
// 90.116 us; speedup vs baseline: 2.8936x; 1.8960x over previous
//
#include <hip/hip_runtime.h>
#include <hip/hip_bf16.h>

// L=4096, B=16, C_IN=512, C_OUT=512, C_COND=512, K=4, HID=128, T=30
typedef __bf16 bfx8 __attribute__((ext_vector_type(8)));
typedef float f32x4 __attribute__((ext_vector_type(4)));
typedef unsigned short u16x8 __attribute__((ext_vector_type(8)));
typedef unsigned short u16x4 __attribute__((ext_vector_type(4)));

__device__ __forceinline__ unsigned short f2bf(float f) {
    unsigned int u = __builtin_bit_cast(unsigned int, f);
    u += 0x7fffu + ((u >> 16) & 1u);          // RNE
    return (unsigned short)(u >> 16);
}

// XOR swizzle within each 2-row (128 B) unit of a [rows][32] bf16 tile.
// chunk = 16B (8 bf16) slot. Returns ushort index of the chunk start.
__device__ __forceinline__ int swz_idx(int row, int chunk) {
    const int p = row >> 1;
    const int q = (((row & 1) << 2) | chunk) ^ (p & 7);
    return p * 64 + q * 8;
}

// ---------- kernel 1: conditioning MLP. One block per b. ----------
__global__ __launch_bounds__(1024) void att_kernel(
    const float* __restrict__ cond, const float* __restrict__ fc1w,
    const float* __restrict__ fc1b, const float* __restrict__ fc2w,
    const float* __restrict__ fc2b, const float* __restrict__ bias,
    float* __restrict__ att_out, float* __restrict__ bagg_out)
{
    __shared__ float h[128];
    __shared__ float att_s[4];
    const int b    = blockIdx.x;
    const int tid  = threadIdx.x;
    const int lane = tid & 63;
    const int wv   = tid >> 6;          // 0..15

    // fc1: 128 outputs, one wave each, 8 iterations
    for (int j = wv; j < 128; j += 16) {
        const float* c = cond + b * 512 + lane * 8;
        const float* w = fc1w + j * 512 + lane * 8;
        const float4 c0 = *(const float4*)c, c1 = *(const float4*)(c + 4);
        const float4 w0 = *(const float4*)w, w1 = *(const float4*)(w + 4);
        float s = c0.x * w0.x + c0.y * w0.y + c0.z * w0.z + c0.w * w0.w
                + c1.x * w1.x + c1.y * w1.y + c1.z * w1.z + c1.w * w1.w;
        #pragma unroll
        for (int off = 32; off; off >>= 1) s += __shfl_down(s, off);
        if (lane == 0) h[j] = fmaxf(s + fc1b[j], 0.0f);
    }
    __syncthreads();

    // fc2: waves 0..3, one k each
    if (wv < 4) {
        const int k = wv;
        float s = h[lane] * fc2w[k * 128 + lane] + h[lane + 64] * fc2w[k * 128 + lane + 64];
        #pragma unroll
        for (int off = 32; off; off >>= 1) s += __shfl_down(s, off);
        if (lane == 0) att_s[k] = (s + fc2b[k]) * (1.0f / 30.0f);
    }
    __syncthreads();

    if (tid == 0) {
        float l0 = att_s[0], l1 = att_s[1], l2 = att_s[2], l3 = att_s[3];
        float m = fmaxf(fmaxf(l0, l1), fmaxf(l2, l3));
        float e0 = expf(l0 - m), e1 = expf(l1 - m), e2 = expf(l2 - m), e3 = expf(l3 - m);
        float inv = 1.0f / (e0 + e1 + e2 + e3);
        att_s[0] = e0 * inv; att_s[1] = e1 * inv; att_s[2] = e2 * inv; att_s[3] = e3 * inv;
        att_out[b * 4 + 0] = att_s[0]; att_out[b * 4 + 1] = att_s[1];
        att_out[b * 4 + 2] = att_s[2]; att_out[b * 4 + 3] = att_s[3];
    }
    __syncthreads();

    if (tid < 512) {
        bagg_out[b * 512 + tid] = att_s[0] * bias[tid] + att_s[1] * bias[512 + tid]
                                + att_s[2] * bias[1024 + tid] + att_s[3] * bias[1536 + tid];
    }
}

// ---------- kernel 2: w_agg[b][o][i] = sum_k att[b][k]*weight[k][o][i], bf16 ----------
__global__ __launch_bounds__(256) void wagg_kernel(
    const float* __restrict__ weight, const float* __restrict__ att,
    unsigned short* __restrict__ wagg)
{
    __shared__ float a_s[64];
    if (threadIdx.x < 64) a_s[threadIdx.x] = att[threadIdx.x];
    __syncthreads();
    const int p = (blockIdx.x * 256 + threadIdx.x) * 4;
    const float4 w0 = *(const float4*)(weight + p);
    const float4 w1 = *(const float4*)(weight + 262144 + p);
    const float4 w2 = *(const float4*)(weight + 524288 + p);
    const float4 w3 = *(const float4*)(weight + 786432 + p);
    #pragma unroll
    for (int b = 0; b < 16; ++b) {
        const float a0 = a_s[4 * b], a1 = a_s[4 * b + 1], a2 = a_s[4 * b + 2], a3 = a_s[4 * b + 3];
        u16x4 r;
        r[0] = f2bf(a0 * w0.x + a1 * w1.x + a2 * w2.x + a3 * w3.x);
        r[1] = f2bf(a0 * w0.y + a1 * w1.y + a2 * w2.y + a3 * w3.y);
        r[2] = f2bf(a0 * w0.z + a1 * w1.z + a2 * w2.z + a3 * w3.z);
        r[3] = f2bf(a0 * w0.w + a1 * w1.w + a2 * w2.w + a3 * w3.w);
        *(u16x4*)(wagg + (size_t)b * 262144 + p) = r;
    }
}

// ---------- kernel 3: out[l][b][o] = sum_i x[l][b][i]*wagg[b][o][i] + bagg[b][o] ----------
// BM=128 (L), BN=512 (all C_OUT), BK=32. 512 threads = 8 waves (2m x 4n), wave 64x128.
// Double-buffered LDS, 2-phase prefetch (issue next-tile loads before current MFMA),
// pair-XOR swizzle on A (both sides) and B (pre-swizzled global source, swizzled read).
__global__ __launch_bounds__(512, 2) void gemm_kernel(
    const float* __restrict__ x, const unsigned short* __restrict__ wagg,
    const float* __restrict__ bagg, float* __restrict__ out)
{
    __shared__ unsigned short As[2][128 * 32];
    __shared__ unsigned short Bs[2][512 * 32];
    __shared__ float bsh[512];

    const int tid = threadIdx.x;
    const int bid = blockIdx.x;
    const int b  = bid >> 5;
    const int l0 = (bid & 31) * 128;

    const int lane = tid & 63;
    const int wid  = tid >> 6;
    const int wm   = wid >> 2;        // 0..1
    const int wn   = wid & 3;         // 0..3
    const int fr   = lane & 15;
    const int fq   = lane >> 4;

    const unsigned short* wb = wagg + (size_t)b * (512 * 512);

    bsh[tid] = bagg[b * 512 + tid];

    f32x4 acc[4][8];
    #pragma unroll
    for (int i = 0; i < 4; ++i)
        #pragma unroll
        for (int j = 0; j < 8; ++j) acc[i][j] = f32x4{0.f, 0.f, 0.f, 0.f};

    // --- A staging geometry: thread covers 8 consecutive floats (one 16B bf16 chunk)
    const int ea   = tid * 8;
    const int arow = ea >> 5;
    const int achk = (ea & 31) >> 3;
    const int aswz = swz_idx(arow, achk);
    const float* xsrc = x + ((size_t)(l0 + arow) * 16 + b) * 512 + (ea & 31);

    // --- B staging: dest slot s -> pre-swizzled global source offset
    int bofs[4];
    #pragma unroll
    for (int it = 0; it < 4; ++it) {
        const int s = it * 512 + tid;     // 16B slot index in the 512x32 tile
        const int p = s >> 3, q = s & 7;
        const int v = q ^ (p & 7);
        const int row = (p << 1) | (v >> 2);
        const int cch = v & 3;
        bofs[it] = row * 512 + cch * 8;
    }

    // --- fragment read indices (loop-invariant, swizzled)
    int aidx[4], bidx[8];
    #pragma unroll
    for (int mf = 0; mf < 4; ++mf) aidx[mf] = swz_idx(wm * 64 + mf * 16 + fr, fq);
    #pragma unroll
    for (int nf = 0; nf < 8; ++nf) bidx[nf] = swz_idx(wn * 128 + nf * 16 + fr, fq);

    // --- prologue: stage kt=0 into buffer 0
    {
        const float4 v0 = *(const float4*)(xsrc);
        const float4 v1 = *(const float4*)(xsrc + 4);
        u16x8 pk;
        pk[0] = f2bf(v0.x); pk[1] = f2bf(v0.y); pk[2] = f2bf(v0.z); pk[3] = f2bf(v0.w);
        pk[4] = f2bf(v1.x); pk[5] = f2bf(v1.y); pk[6] = f2bf(v1.z); pk[7] = f2bf(v1.w);
        *(u16x8*)&As[0][aswz] = pk;
        #pragma unroll
        for (int it = 0; it < 4; ++it) {
            char* dst = (char*)&Bs[0][0] + it * 8192 + tid * 16;
            __builtin_amdgcn_global_load_lds(
                (const __attribute__((address_space(1))) void*)(wb + bofs[it]),
                (__attribute__((address_space(3))) void*)dst, 16, 0, 0);
        }
    }
    __syncthreads();

    int cur = 0;
    for (int kt = 0; kt < 16; ++kt) {
        const int nxt = cur ^ 1;
        float4 v0, v1;
        // issue next tile's loads first (overlap with this tile's compute)
        if (kt < 15) {
            const int k0n = (kt + 1) * 32;
            #pragma unroll
            for (int it = 0; it < 4; ++it) {
                char* dst = (char*)&Bs[nxt][0] + it * 8192 + tid * 16;
                __builtin_amdgcn_global_load_lds(
                    (const __attribute__((address_space(1))) void*)(wb + bofs[it] + k0n),
                    (__attribute__((address_space(3))) void*)dst, 16, 0, 0);
            }
            v0 = *(const float4*)(xsrc + k0n);
            v1 = *(const float4*)(xsrc + k0n + 4);
        }
        // current tile: fragments + MFMA
        bfx8 af[4], bfr[8];
        #pragma unroll
        for (int mf = 0; mf < 4; ++mf)
            af[mf] = *reinterpret_cast<const bfx8*>(&As[cur][aidx[mf]]);
        #pragma unroll
        for (int nf = 0; nf < 8; ++nf)
            bfr[nf] = *reinterpret_cast<const bfx8*>(&Bs[cur][bidx[nf]]);
        #pragma unroll
        for (int mf = 0; mf < 4; ++mf)
            #pragma unroll
            for (int nf = 0; nf < 8; ++nf)
                acc[mf][nf] = __builtin_amdgcn_mfma_f32_16x16x32_bf16(af[mf], bfr[nf], acc[mf][nf], 0, 0, 0);
        // write next A tile (regs -> LDS), then barrier
        if (kt < 15) {
            u16x8 pk;
            pk[0] = f2bf(v0.x); pk[1] = f2bf(v0.y); pk[2] = f2bf(v0.z); pk[3] = f2bf(v0.w);
            pk[4] = f2bf(v1.x); pk[5] = f2bf(v1.y); pk[6] = f2bf(v1.z); pk[7] = f2bf(v1.w);
            *(u16x8*)&As[nxt][aswz] = pk;
            __syncthreads();
            cur = nxt;
        }
    }

    // --- epilogue: C/D map col=lane&15 (n), row=(lane>>4)*4+r (m) ---
    #pragma unroll
    for (int mf = 0; mf < 4; ++mf) {
        #pragma unroll
        for (int nf = 0; nf < 8; ++nf) {
            const int o = wn * 128 + nf * 16 + fr;
            const float bb = bsh[o];
            const int lrow = l0 + wm * 64 + mf * 16 + fq * 4;
            float* op = out + ((size_t)lrow * 16 + b) * 512 + o;
            const f32x4 a = acc[mf][nf];
            op[0]        = a[0] + bb;
            op[8192]     = a[1] + bb;
            op[2 * 8192] = a[2] + bb;
            op[3 * 8192] = a[3] + bb;
        }
    }
}

extern "C" void kernel_launch(void* const* d_in, const int* in_sizes, int n_in,
                              void* d_out, int out_size, void* d_ws, size_t ws_size,
                              hipStream_t stream) {
    const float* x      = (const float*)d_in[0];
    const float* cond   = (const float*)d_in[1];
    const float* fc1w   = (const float*)d_in[2];
    const float* fc1b   = (const float*)d_in[3];
    const float* fc2w   = (const float*)d_in[4];
    const float* fc2b   = (const float*)d_in[5];
    const float* weight = (const float*)d_in[6];
    const float* bias   = (const float*)d_in[7];
    float* out = (float*)d_out;

    char* ws = (char*)d_ws;
    float* att_ws  = (float*)ws;                       // 64 f32
    float* bagg_ws = (float*)(ws + 1024);              // 8192 f32
    unsigned short* wagg_ws = (unsigned short*)(ws + 65536);  // 8 MiB bf16

    att_kernel<<<16, 1024, 0, stream>>>(cond, fc1w, fc1b, fc2w, fc2b, bias, att_ws, bagg_ws);
    wagg_kernel<<<256, 256, 0, stream>>>(weight, att_ws, wagg_ws);
    gemm_kernel<<<512, 512, 0, stream>>>(x, wagg_ws, bagg_ws, out);
}